// Round 6
// baseline (46.653 us; speedup 1.0000x reference)
//
#include <hip/hip_runtime.h>
#include <math.h>

namespace {

constexpr int Bg   = 2048;   // graphs
constexpr int Nn   = 256;    // nodes per graph
constexpr int Dd   = 128;    // node embed dim
constexpr int Hh   = 4;      // heads
constexpr int SUBn = 32;     // nodes per subset
constexpr int DHd  = 128;    // head embed dim
constexpr int D3   = 384;    // 3*D
constexpr int DH2  = 256;    // 2*DH
constexpr int Gg   = 16;     // graphs per block
constexpr int XP   = 392;    // X lds row stride (bf16 elems)
constexpr int HP   = 264;    // H1 lds row stride
constexpr float EPSf = 1e-5f;

typedef __attribute__((ext_vector_type(8))) short bf16x8;
typedef __attribute__((ext_vector_type(4))) float f32x4;

__device__ __forceinline__ unsigned short bf_rne(float f) {
    union { float f; unsigned int u; } v; v.f = f;
    const unsigned int u = v.u + 0x7FFFu + ((v.u >> 16) & 1u);
    return (unsigned short)(u >> 16);
}

// ------------------------------------------------------------------
// Kernel 0: prep — W1/W2 transpose to bf16 [j][k] + per-graph offsets
// ------------------------------------------------------------------
__global__ __launch_bounds__(256)
void prep_k(const float* __restrict__ w1, const float* __restrict__ w2,
            const int* __restrict__ batch,
            unsigned short* __restrict__ wt1, unsigned short* __restrict__ wt2,
            int* __restrict__ offs)
{
    const int bid = (int)blockIdx.x;
    const int t   = (int)threadIdx.x;

    if (bid >= 128) {
        const int i = (bid - 128) * 256 + t;
        const int v = batch[i];
        if (i == 0 || batch[i - 1] != v) offs[v] = i;
        return;
    }

    __shared__ float tile[64][65];
    const float* src; unsigned short* dst; int K, J, k0, j0;
    if (bid < 96) {
        const int hb = bid / 24, tl = bid % 24;
        k0 = (tl % 6) * 64; j0 = (tl / 6) * 64;
        K = D3; J = DH2;
        src = w1 + (size_t)hb * D3 * DH2;
        dst = wt1 + (size_t)hb * DH2 * D3;
    } else {
        const int b2 = bid - 96, hb = b2 / 8, tl = b2 % 8;
        k0 = (tl % 4) * 64; j0 = (tl / 4) * 64;
        K = DH2; J = DHd;
        src = w2 + (size_t)hb * DH2 * DHd;
        dst = wt2 + (size_t)hb * DHd * DH2;
    }

    #pragma unroll
    for (int it = 0; it < 16; ++it) {
        const int idx = it * 256 + t;
        tile[idx >> 6][idx & 63] =
            src[(size_t)(k0 + (idx >> 6)) * J + (j0 + (idx & 63))];
    }
    __syncthreads();
    #pragma unroll
    for (int it = 0; it < 16; ++it) {
        const int idx = it * 256 + t;
        const int jr = idx >> 6, kc = idx & 63;
        dst[(size_t)(j0 + jr) * K + (k0 + kc)] = bf_rne(tile[kc][jr]);
    }
}

// ------------------------------------------------------------------
// Kernel 1: FUSED gather+reduce+MLP. 512 blocks x 512 threads.
// Phase A: thread = (graph, chunk) 16x32; each thread reduces one float4
//          column over 32 rows; 16 reading waves/CU, unroll 8.
// Phase B: 8 waves split j-ranges; mfma_f32_16x16x32_bf16.
// ------------------------------------------------------------------
__global__ __launch_bounds__(512, 4)
void fused_k(const float* __restrict__ emb,
             const unsigned short* __restrict__ wt1,
             const unsigned short* __restrict__ wt2,
             const int* __restrict__ subset,
             const int* __restrict__ offs,
             const float* __restrict__ b1, const float* __restrict__ g1,
             const float* __restrict__ be1,
             const float* __restrict__ b2, const float* __restrict__ g2,
             const float* __restrict__ be2,
             float* __restrict__ out)
{
    __shared__ __align__(16) unsigned short X[Gg * XP];    // 12.5 KB
    __shared__ __align__(16) unsigned short H1s[Gg * HP];  // 8.4 KB
    __shared__ float red[2][8][Gg];                        // 1 KB
    __shared__ int sn[SUBn];
    __shared__ int soff[Gg];

    const int t   = (int)threadIdx.x;
    const int bid = (int)blockIdx.x;
    const int xcd = bid & 7, slot = bid >> 3;
    const int head = xcd >> 1;
    const int gblk = ((xcd & 1) << 6) + slot;
    const int gbase = gblk * Gg;

    if (t < SUBn) sn[t] = subset[head * SUBn + t];
    if (t >= 64 && t < 64 + Gg) soff[t - 64] = offs[gbase + (t - 64)];
    __syncthreads();

    // ---------- Phase A: gather + mean/max/sum -> X (bf16 LDS) ----------
    {
        const int g  = t >> 5;       // graph 0..15
        const int ch = t & 31;       // float4 chunk 0..31 of the 512B row
        const float* base = emb + (size_t)soff[g] * Dd + ch * 4;

        float sx = 0.f, sy = 0.f, sz = 0.f, sw = 0.f;
        float mx = -INFINITY, my = -INFINITY, mz = -INFINITY, mw = -INFINITY;

        #pragma unroll 8
        for (int s = 0; s < SUBn; ++s) {
            const float4 v = *reinterpret_cast<const float4*>(
                base + (size_t)sn[s] * Dd);
            sx += v.x; sy += v.y; sz += v.z; sw += v.w;
            mx = fmaxf(mx, v.x); my = fmaxf(my, v.y);
            mz = fmaxf(mz, v.z); mw = fmaxf(mw, v.w);
        }

        unsigned short* xr = X + g * XP;
        const int d = ch * 4;
        *reinterpret_cast<ushort4*>(xr + d) =
            make_ushort4(bf_rne(sx * 0.03125f), bf_rne(sy * 0.03125f),
                         bf_rne(sz * 0.03125f), bf_rne(sw * 0.03125f));
        *reinterpret_cast<ushort4*>(xr + Dd + d) =
            make_ushort4(bf_rne(mx), bf_rne(my), bf_rne(mz), bf_rne(mw));
        *reinterpret_cast<ushort4*>(xr + 2 * Dd + d) =
            make_ushort4(bf_rne(sx), bf_rne(sy), bf_rne(sz), bf_rne(sw));
    }
    __syncthreads();

    const int lane = t & 63, wv = t >> 6;       // wv 0..7
    const int lrow = lane & 15, q = lane >> 4;

    // ---------- proj1: [16 x 384] x [384 x 256], wave wv -> j in [wv*32, wv*32+32) ----------
    bf16x8 a1[12];
    #pragma unroll
    for (int k0 = 0; k0 < 12; ++k0)
        a1[k0] = *reinterpret_cast<const bf16x8*>(X + lrow * XP + k0 * 32 + q * 8);

    f32x4 acc[2];
    #pragma unroll
    for (int jt = 0; jt < 2; ++jt) {
        const int j = wv * 32 + jt * 16 + lrow;
        const float bj = b1[head * DH2 + j];
        f32x4 c = {bj, bj, bj, bj};
        const unsigned short* wp = wt1 + ((size_t)head * DH2 + j) * D3 + q * 8;
        #pragma unroll
        for (int k0 = 0; k0 < 12; ++k0)
            c = __builtin_amdgcn_mfma_f32_16x16x32_bf16(
                    a1[k0], *reinterpret_cast<const bf16x8*>(wp + k0 * 32), c, 0, 0, 0);
        acc[jt] = c;
    }

    // ---------- LN1 + ReLU -> H1 (bf16 LDS) ----------
    {
        float s1[4], s2[4];
        #pragma unroll
        for (int r = 0; r < 4; ++r) {
            float a = acc[0][r] + acc[1][r];
            float b = acc[0][r] * acc[0][r] + acc[1][r] * acc[1][r];
            #pragma unroll
            for (int m = 1; m < 16; m <<= 1) {
                a += __shfl_xor(a, m, 64);
                b += __shfl_xor(b, m, 64);
            }
            s1[r] = a; s2[r] = b;
        }
        if (lrow == 0) {
            #pragma unroll
            for (int r = 0; r < 4; ++r) {
                red[0][wv][q * 4 + r] = s1[r];
                red[1][wv][q * 4 + r] = s2[r];
            }
        }
        __syncthreads();

        float t1[4] = {0.f, 0.f, 0.f, 0.f}, t2[4] = {0.f, 0.f, 0.f, 0.f};
        #pragma unroll
        for (int w = 0; w < 8; ++w) {
            const float4 r1 = *reinterpret_cast<const float4*>(&red[0][w][q * 4]);
            const float4 r2 = *reinterpret_cast<const float4*>(&red[1][w][q * 4]);
            t1[0] += r1.x; t1[1] += r1.y; t1[2] += r1.z; t1[3] += r1.w;
            t2[0] += r2.x; t2[1] += r2.y; t2[2] += r2.z; t2[3] += r2.w;
        }
        float mean[4], rstd[4];
        #pragma unroll
        for (int r = 0; r < 4; ++r) {
            mean[r] = t1[r] * (1.f / 256.f);
            const float var = t2[r] * (1.f / 256.f) - mean[r] * mean[r];
            rstd[r] = rsqrtf(var + EPSf);
        }
        #pragma unroll
        for (int jt = 0; jt < 2; ++jt) {
            const int j = wv * 32 + jt * 16 + lrow;
            const float gj = g1[j], bj = be1[j];
            #pragma unroll
            for (int r = 0; r < 4; ++r) {
                const float h = fmaxf(0.f, (acc[jt][r] - mean[r]) * rstd[r] * gj + bj);
                H1s[(q * 4 + r) * HP + j] = bf_rne(h);
            }
        }
    }
    __syncthreads();

    // ---------- proj2: [16 x 256] x [256 x 128], wave wv -> j in [wv*16, wv*16+16) ----------
    bf16x8 a2[8];
    #pragma unroll
    for (int k0 = 0; k0 < 8; ++k0)
        a2[k0] = *reinterpret_cast<const bf16x8*>(H1s + lrow * HP + k0 * 32 + q * 8);

    f32x4 acc2;
    {
        const int j = wv * 16 + lrow;
        const float bj = b2[head * DHd + j];
        f32x4 c = {bj, bj, bj, bj};
        const unsigned short* wp = wt2 + ((size_t)head * DHd + j) * DH2 + q * 8;
        #pragma unroll
        for (int k0 = 0; k0 < 8; ++k0)
            c = __builtin_amdgcn_mfma_f32_16x16x32_bf16(
                    a2[k0], *reinterpret_cast<const bf16x8*>(wp + k0 * 32), c, 0, 0, 0);
        acc2 = c;
    }

    // ---------- LN2 + ReLU -> out ----------
    {
        float s1[4], s2[4];
        #pragma unroll
        for (int r = 0; r < 4; ++r) {
            float a = acc2[r];
            float b = acc2[r] * acc2[r];
            #pragma unroll
            for (int m = 1; m < 16; m <<= 1) {
                a += __shfl_xor(a, m, 64);
                b += __shfl_xor(b, m, 64);
            }
            s1[r] = a; s2[r] = b;
        }
        __syncthreads();
        if (lrow == 0) {
            #pragma unroll
            for (int r = 0; r < 4; ++r) {
                red[0][wv][q * 4 + r] = s1[r];
                red[1][wv][q * 4 + r] = s2[r];
            }
        }
        __syncthreads();

        float t1[4] = {0.f, 0.f, 0.f, 0.f}, t2[4] = {0.f, 0.f, 0.f, 0.f};
        #pragma unroll
        for (int w = 0; w < 8; ++w) {
            const float4 r1 = *reinterpret_cast<const float4*>(&red[0][w][q * 4]);
            const float4 r2 = *reinterpret_cast<const float4*>(&red[1][w][q * 4]);
            t1[0] += r1.x; t1[1] += r1.y; t1[2] += r1.z; t1[3] += r1.w;
            t2[0] += r2.x; t2[1] += r2.y; t2[2] += r2.z; t2[3] += r2.w;
        }
        const int j = wv * 16 + lrow;
        const float gj = g2[j], bj = be2[j];
        #pragma unroll
        for (int r = 0; r < 4; ++r) {
            const float mean = t1[r] * (1.f / 128.f);
            const float var  = t2[r] * (1.f / 128.f) - mean * mean;
            const float rstd = rsqrtf(var + EPSf);
            const float o = fmaxf(0.f, (acc2[r] - mean) * rstd * gj + bj);
            out[(size_t)(gbase + q * 4 + r) * (Hh * DHd) + head * DHd + j] = o;
        }
    }
}

} // namespace

extern "C" void kernel_launch(void* const* d_in, const int* in_sizes, int n_in,
                              void* d_out, int out_size, void* d_ws, size_t ws_size,
                              hipStream_t stream) {
    const float* emb  = (const float*)d_in[0];
    const float* w1   = (const float*)d_in[1];
    const float* b1   = (const float*)d_in[2];
    const float* g1   = (const float*)d_in[3];
    const float* be1  = (const float*)d_in[4];
    const float* w2   = (const float*)d_in[5];
    const float* b2   = (const float*)d_in[6];
    const float* g2   = (const float*)d_in[7];
    const float* be2  = (const float*)d_in[8];
    const int* subset = (const int*)d_in[9];
    const int* batch  = (const int*)d_in[11];
    float* out = (float*)d_out;

    int* offs = (int*)d_ws;                                            // 8 KB
    unsigned short* wt1 = (unsigned short*)((char*)d_ws + 16384);      // 4*256*384 bf16
    unsigned short* wt2 = wt1 + (size_t)Hh * DH2 * D3;                 // 4*128*256 bf16

    prep_k <<<dim3(128 + Bg * Nn / 256), dim3(256), 0, stream>>>(w1, w2, batch,
                                                                 wt1, wt2, offs);
    fused_k<<<dim3(Hh * (Bg / Gg)), dim3(512), 0, stream>>>(emb, wt1, wt2,
                                                            subset, offs,
                                                            b1, g1, be1,
                                                            b2, g2, be2, out);
}